// Round 1
// baseline (381.978 us; speedup 1.0000x reference)
//
#include <hip/hip_runtime.h>
#include <math.h>

// Problem constants
#define BS 4
#define LQ 1024
#define EMB 256
#define NH 8
#define NL 4
#define NP 16
#define HD 32
#define LV 5440   // 64*64 + 32*32 + 16*16 + 8*8

// ---------------- fp32 tiled GEMM: C = A[M,K] @ B[K,N] + bias[N] ----------------
// 128x128 tile, 256 threads, 8x8 per thread, BK=16. M%128==0, N%128==0, K%16==0.
#define BM 128
#define BN 128
#define BK 16

__global__ __launch_bounds__(256) void gemm_bias(const float* __restrict__ A,
                                                 const float* __restrict__ B,
                                                 const float* __restrict__ bias,
                                                 float* __restrict__ C,
                                                 int M, int N, int K) {
    __shared__ float As[BK][BM + 4];
    __shared__ float Bs[BK][BN + 4];
    const int t  = threadIdx.x;
    const int tx = t & 15;   // col group 0..15
    const int ty = t >> 4;   // row group 0..15
    const int row0 = blockIdx.y * BM;
    const int col0 = blockIdx.x * BN;

    float acc[8][8];
#pragma unroll
    for (int i = 0; i < 8; ++i)
#pragma unroll
        for (int j = 0; j < 8; ++j) acc[i][j] = 0.f;

    const int ar = t >> 1;         // A row in tile 0..127
    const int ak = (t & 1) * 8;    // k offset 0 or 8
    const int bk = t >> 4;         // B k in tile 0..15
    const int bc = (t & 15) * 8;   // B col offset

    for (int k0 = 0; k0 < K; k0 += BK) {
        const float4* ap = (const float4*)(A + (size_t)(row0 + ar) * K + k0 + ak);
        float4 a0 = ap[0], a1 = ap[1];
        const float4* bp = (const float4*)(B + (size_t)(k0 + bk) * N + col0 + bc);
        float4 b0 = bp[0], b1 = bp[1];

        __syncthreads();  // previous inner loop done before overwrite
        As[ak + 0][ar] = a0.x; As[ak + 1][ar] = a0.y;
        As[ak + 2][ar] = a0.z; As[ak + 3][ar] = a0.w;
        As[ak + 4][ar] = a1.x; As[ak + 5][ar] = a1.y;
        As[ak + 6][ar] = a1.z; As[ak + 7][ar] = a1.w;
        *(float4*)&Bs[bk][bc]     = b0;
        *(float4*)&Bs[bk][bc + 4] = b1;
        __syncthreads();

#pragma unroll
        for (int kk = 0; kk < BK; ++kk) {
            float a[8], b[8];
            *(float4*)(a)     = *(const float4*)&As[kk][ty * 8];
            *(float4*)(a + 4) = *(const float4*)&As[kk][ty * 8 + 4];
            *(float4*)(b)     = *(const float4*)&Bs[kk][tx * 8];
            *(float4*)(b + 4) = *(const float4*)&Bs[kk][tx * 8 + 4];
#pragma unroll
            for (int i = 0; i < 8; ++i)
#pragma unroll
                for (int j = 0; j < 8; ++j) acc[i][j] = fmaf(a[i], b[j], acc[i][j]);
        }
    }

#pragma unroll
    for (int i = 0; i < 8; ++i) {
        const int r = row0 + ty * 8 + i;
        const int c = col0 + tx * 8;
        float4 o0, o1;
        o0.x = acc[i][0] + bias[c + 0]; o0.y = acc[i][1] + bias[c + 1];
        o0.z = acc[i][2] + bias[c + 2]; o0.w = acc[i][3] + bias[c + 3];
        o1.x = acc[i][4] + bias[c + 4]; o1.y = acc[i][5] + bias[c + 5];
        o1.z = acc[i][6] + bias[c + 6]; o1.w = acc[i][7] + bias[c + 7];
        *(float4*)(C + (size_t)r * N + c)     = o0;
        *(float4*)(C + (size_t)r * N + c + 4) = o1;
    }
}

// ---------------- location epilogue: loc = poly(refp, lambda_p) + raw/norm ------
// In-place on d_out loc region. One thread per sample point (x and y coords).
__global__ __launch_bounds__(256) void loc_kernel(const float* __restrict__ refp,
                                                  float* __restrict__ loc) {
    const int t = blockIdx.x * 256 + threadIdx.x;  // 0 .. 2097151, [b][q][h][l][p]
    const int p  = t & 15;
    const int l  = (t >> 4) & 3;
    const int bq = t >> 9;                         // b*1024 + q
    const float* rp = refp + (size_t)bq * 8;       // [2][4] poly coeffs
    const float lam = (float)p * (1.0f / 15.0f);
    const float l2 = lam * lam, l3 = l2 * lam;
    const float px = rp[0] * l3 + rp[1] * l2 + rp[2] * lam + rp[3];
    const float py = rp[4] * l3 + rp[5] * l2 + rp[6] * lam + rp[7];
    const float Wf = (float)(64 >> l);             // square levels: Wl == Hl
    float* o = loc + (size_t)t * 2;
    o[0] = px + o[0] / Wf;
    o[1] = py + o[1] / Wf;
}

// ---------------- softmax over 64 contiguous logits, one wave per row ------------
__global__ __launch_bounds__(256) void softmax64(float* __restrict__ a) {
    const int row  = blockIdx.x * 4 + (threadIdx.x >> 6);
    const int lane = threadIdx.x & 63;
    float* p = a + (size_t)row * 64 + lane;
    float v = *p;
    float m = v;
#pragma unroll
    for (int off = 32; off; off >>= 1) m = fmaxf(m, __shfl_xor(m, off));
    float e = expf(v - m);
    float s = e;
#pragma unroll
    for (int off = 32; off; off >>= 1) s += __shfl_xor(s, off);
    *p = e / s;
}

// ---------------- bilinear sampling + attention weighting ------------------------
// One 32-lane group per (b,q,h); lane = channel d. Corner loads are coalesced
// 128B rows of v. Scalar loc/weight math is redundantly computed per-lane
// (same-address loads broadcast).
__global__ __launch_bounds__(256) void sample_kernel(const float* __restrict__ v,
                                                     const float* __restrict__ loc,
                                                     const float* __restrict__ attn,
                                                     float* __restrict__ out) {
    const int gid = blockIdx.x * 8 + (threadIdx.x >> 5);  // (b*1024+q)*8 + h
    const int d   = threadIdx.x & 31;
    const int h   = gid & 7;
    const int bq  = gid >> 3;
    const int b   = bq >> 10;
    const float* lp = loc  + (size_t)gid * 128;  // [l][p][2]
    const float* ap = attn + (size_t)gid * 64;   // [l][p]
    const float* vb = v + (size_t)b * LV * EMB + h * HD + d;

    float acc = 0.f;
    int start = 0;
#pragma unroll
    for (int l = 0; l < 4; ++l) {
        const int W = 64 >> l;
        const float Wf = (float)W;
        const float* vl = vb + (size_t)start * EMB;
        for (int p = 0; p < 16; ++p) {
            const int i = l * 16 + p;
            const float lx = lp[2 * i], ly = lp[2 * i + 1];
            const float w  = ap[i];
            const float x = lx * Wf - 0.5f;
            const float y = ly * Wf - 0.5f;
            const float x0f = floorf(x), y0f = floorf(y);
            const float wx = x - x0f, wy = y - y0f;
            const int x0 = (int)x0f, y0 = (int)y0f;
            const int x1 = x0 + 1,  y1 = y0 + 1;
            const float w00 = (1.f - wx) * (1.f - wy) * w;
            const float w10 = wx * (1.f - wy) * w;
            const float w01 = (1.f - wx) * wy * w;
            const float w11 = wx * wy * w;
            const bool vx0 = (x0 >= 0) & (x0 < W);
            const bool vx1 = (x1 >= 0) & (x1 < W);
            const bool vy0 = (y0 >= 0) & (y0 < W);
            const bool vy1 = (y1 >= 0) & (y1 < W);
            const int cx0 = min(max(x0, 0), W - 1);
            const int cx1 = min(max(x1, 0), W - 1);
            const int cy0 = min(max(y0, 0), W - 1);
            const int cy1 = min(max(y1, 0), W - 1);
            const float g00 = vl[(size_t)(cy0 * W + cx0) * EMB];
            const float g10 = vl[(size_t)(cy0 * W + cx1) * EMB];
            const float g01 = vl[(size_t)(cy1 * W + cx0) * EMB];
            const float g11 = vl[(size_t)(cy1 * W + cx1) * EMB];
            acc += ((vx0 & vy0) ? w00 : 0.f) * g00;
            acc += ((vx1 & vy0) ? w10 : 0.f) * g10;
            acc += ((vx0 & vy1) ? w01 : 0.f) * g01;
            acc += ((vx1 & vy1) ? w11 : 0.f) * g11;
        }
        start += W * W;
    }
    out[(size_t)gid * HD + d] = acc;
}

// ---------------- host launch ----------------------------------------------------
extern "C" void kernel_launch(void* const* d_in, const int* in_sizes, int n_in,
                              void* d_out, int out_size, void* d_ws, size_t ws_size,
                              hipStream_t stream) {
    const float* query   = (const float*)d_in[0];
    const float* refp    = (const float*)d_in[1];
    const float* value   = (const float*)d_in[2];
    const float* W_value = (const float*)d_in[3];
    const float* b_value = (const float*)d_in[4];
    const float* W_off   = (const float*)d_in[5];
    const float* b_off   = (const float*)d_in[6];
    const float* W_attn  = (const float*)d_in[7];
    const float* b_attn  = (const float*)d_in[8];
    const float* W_out   = (const float*)d_in[9];
    const float* b_out   = (const float*)d_in[10];

    float* out      = (float*)d_out;            // [4,1024,256]           = 1,048,576
    float* loc_out  = out + 1048576;            // [4,1024,8,4,16,2]      = 4,194,304
    float* attn_out = out + 5242880;            // [4,1024,8,4,16]        = 2,097,152

    float* v_proj = (float*)d_ws;               // [4,5440,8,32] = 5,570,560 floats
    float* interm = v_proj + 5570560;           // [4,1024,8,32] = 1,048,576 floats

    const dim3 blk(256);
    const int Mv = BS * LV;   // 21760
    const int Mq = BS * LQ;   // 4096

    // v = value @ W_value + b_value
    gemm_bias<<<dim3(EMB / BN, Mv / BM), blk, 0, stream>>>(value, W_value, b_value,
                                                           v_proj, Mv, EMB, EMB);
    // raw offsets -> d_out loc region
    gemm_bias<<<dim3(1024 / BN, Mq / BM), blk, 0, stream>>>(query, W_off, b_off,
                                                            loc_out, Mq, 1024, EMB);
    // attn logits -> d_out attn region
    gemm_bias<<<dim3(512 / BN, Mq / BM), blk, 0, stream>>>(query, W_attn, b_attn,
                                                           attn_out, Mq, 512, EMB);
    // loc = poly(refp) + raw/normalizer, in place
    loc_kernel<<<2097152 / 256, blk, 0, stream>>>(refp, loc_out);
    // softmax over 64, in place
    softmax64<<<(BS * LQ * NH) / 4, blk, 0, stream>>>(attn_out);
    // bilinear gather + attention weighting
    sample_kernel<<<(BS * LQ * NH) / 8, blk, 0, stream>>>(v_proj, loc_out, attn_out, interm);
    // output = interm @ W_out + b_out
    gemm_bias<<<dim3(EMB / BN, Mq / BM), blk, 0, stream>>>(interm, W_out, b_out,
                                                           out, Mq, EMB, EMB);
}

// Round 2
// 201.746 us; speedup vs baseline: 1.8934x; 1.8934x over previous
//
#include <hip/hip_runtime.h>
#include <math.h>

// Problem constants
#define BS 4
#define LQ 1024
#define EMB 256
#define NH 8
#define NL 4
#define NP 16
#define HD 32
#define LV 5440   // 64*64 + 32*32 + 16*16 + 8*8
#define KDIM 256  // all GEMMs have K = 256

typedef __attribute__((ext_vector_type(8))) short short8;  // 8 bf16 = 4 VGPRs
typedef __attribute__((ext_vector_type(4))) float f32x4;

__device__ inline unsigned short f2bf(float f) {
    unsigned u = __builtin_bit_cast(unsigned, f);
    u += 0x7fff + ((u >> 16) & 1);   // round-to-nearest-even
    return (unsigned short)(u >> 16);
}

// ---------- W[K=256][N] fp32  ->  Wt[N][256] bf16 (transpose + convert) ----------
__global__ __launch_bounds__(256) void convT(const float* __restrict__ W,
                                             unsigned short* __restrict__ Wt, int N) {
    __shared__ float tile[32][33];
    const int n0 = blockIdx.x * 32, k0 = blockIdx.y * 32;
    const int tx = threadIdx.x & 31, ty = threadIdx.x >> 5;  // ty 0..7
#pragma unroll
    for (int i = 0; i < 32; i += 8)
        tile[ty + i][tx] = W[(size_t)(k0 + ty + i) * N + n0 + tx];
    __syncthreads();
#pragma unroll
    for (int i = 0; i < 32; i += 8)
        Wt[(size_t)(n0 + ty + i) * KDIM + k0 + tx] = f2bf(tile[tx][ty + i]);
}

// ---------------- bf16 MFMA GEMM: C[M][N] = A[M][256] @ Bt[N][256]^T + bias -------
// 64x64 tile, 256 threads (4 waves, 2x2 wave grid of 32x32), BK=32, K=256 fixed.
// A: fp32 in global (converted during staging) when A_FP32, else bf16 (glds).
// Bt: bf16 row-major [N][K] -> staged via global_load_lds width 16.
// LDS layouts K-contiguous: As[m][k], Bs[n][k] (both 64x32 bf16, no padding —
// each wave's fragment read sweeps a contiguous 1KB block: conflict-free).
template <bool A_FP32>
__global__ __launch_bounds__(256) void gemm_mfma(const void* __restrict__ Aptr,
                                                 const unsigned short* __restrict__ Bt,
                                                 const float* __restrict__ bias,
                                                 float* __restrict__ C,
                                                 int M, int N) {
    __shared__ short As[64 * 32];
    __shared__ short Bs[64 * 32];
    const int t = threadIdx.x;
    const int lane = t & 63, w = t >> 6;
    const int quad = lane >> 4, l16 = lane & 15;
    const int row0 = blockIdx.y * 64, col0 = blockIdx.x * 64;

    f32x4 acc00 = {}, acc01 = {}, acc10 = {}, acc11 = {};

    // staging: chunk c = t covers 8 bf16: row m=c>>2, k-offset (c&3)*8
    const int sm = t >> 2, sko = (t & 3) * 8;
    const unsigned short* bsrc = Bt + (size_t)(col0 + sm) * KDIM + sko;
    const float* afsrc = (const float*)Aptr + (size_t)(row0 + sm) * KDIM + sko;
    const unsigned short* absrc = (const unsigned short*)Aptr + (size_t)(row0 + sm) * KDIM + sko;
    short* const as_dst = As + t * 8;
    short* const bs_wbase = Bs + w * 512;   // wave-uniform glds base (lane*16B appended by HW)
    short* const as_wbase = As + w * 512;

    const int mrow = 32 * (w >> 1);   // wave row base in tile
    const int ncol = 32 * (w & 1);    // wave col base in tile

    for (int kt = 0; kt < KDIM / 32; ++kt) {
        __syncthreads();   // prior compute done reading LDS
        __builtin_amdgcn_global_load_lds(
            (const __attribute__((address_space(1))) void*)(bsrc + kt * 32),
            (__attribute__((address_space(3))) void*)bs_wbase, 16, 0, 0);
        if (A_FP32) {
            const float* s = afsrc + kt * 32;
            float4 f0 = *(const float4*)s, f1 = *(const float4*)(s + 4);
            short8 ah;
            ah[0] = (short)f2bf(f0.x); ah[1] = (short)f2bf(f0.y);
            ah[2] = (short)f2bf(f0.z); ah[3] = (short)f2bf(f0.w);
            ah[4] = (short)f2bf(f1.x); ah[5] = (short)f2bf(f1.y);
            ah[6] = (short)f2bf(f1.z); ah[7] = (short)f2bf(f1.w);
            *(short8*)as_dst = ah;
        } else {
            __builtin_amdgcn_global_load_lds(
                (const __attribute__((address_space(1))) void*)(absrc + kt * 32),
                (__attribute__((address_space(3))) void*)as_wbase, 16, 0, 0);
        }
        __syncthreads();   // drains vmcnt+lgkmcnt: tiles ready

        short8 a0 = *(const short8*)&As[(mrow + l16) * 32 + quad * 8];
        short8 a1 = *(const short8*)&As[(mrow + 16 + l16) * 32 + quad * 8];
        short8 b0 = *(const short8*)&Bs[(ncol + l16) * 32 + quad * 8];
        short8 b1 = *(const short8*)&Bs[(ncol + 16 + l16) * 32 + quad * 8];
        acc00 = __builtin_amdgcn_mfma_f32_16x16x32_bf16(a0, b0, acc00, 0, 0, 0);
        acc01 = __builtin_amdgcn_mfma_f32_16x16x32_bf16(a0, b1, acc01, 0, 0, 0);
        acc10 = __builtin_amdgcn_mfma_f32_16x16x32_bf16(a1, b0, acc10, 0, 0, 0);
        acc11 = __builtin_amdgcn_mfma_f32_16x16x32_bf16(a1, b1, acc11, 0, 0, 0);
    }

    // C/D layout: col = lane&15, row = quad*4 + reg  [m89-verified]
#pragma unroll
    for (int ni = 0; ni < 2; ++ni) {
        const int c = col0 + ncol + 16 * ni + l16;
        const float bv = bias[c];
#pragma unroll
        for (int mi = 0; mi < 2; ++mi) {
            const f32x4 a = (mi == 0) ? (ni == 0 ? acc00 : acc01)
                                      : (ni == 0 ? acc10 : acc11);
            const int r0 = row0 + mrow + 16 * mi + quad * 4;
#pragma unroll
            for (int r = 0; r < 4; ++r)
                C[(size_t)(r0 + r) * N + c] = a[r] + bv;
        }
    }
}

// ---------------- location epilogue: loc = poly(refp, lambda_p) + raw/norm ------
__global__ __launch_bounds__(256) void loc_kernel(const float* __restrict__ refp,
                                                  float* __restrict__ loc) {
    const int t = blockIdx.x * 256 + threadIdx.x;  // [b][q][h][l][p]
    const int p  = t & 15;
    const int l  = (t >> 4) & 3;
    const int bq = t >> 9;
    const float* rp = refp + (size_t)bq * 8;
    const float lam = (float)p * (1.0f / 15.0f);
    const float l2 = lam * lam, l3 = l2 * lam;
    const float px = rp[0] * l3 + rp[1] * l2 + rp[2] * lam + rp[3];
    const float py = rp[4] * l3 + rp[5] * l2 + rp[6] * lam + rp[7];
    const float Wf = (float)(64 >> l);
    float* o = loc + (size_t)t * 2;
    o[0] = px + o[0] / Wf;
    o[1] = py + o[1] / Wf;
}

// ---------------- softmax over 64 contiguous logits, one wave per row ------------
__global__ __launch_bounds__(256) void softmax64(float* __restrict__ a) {
    const int row  = blockIdx.x * 4 + (threadIdx.x >> 6);
    const int lane = threadIdx.x & 63;
    float* p = a + (size_t)row * 64 + lane;
    float v = *p;
    float m = v;
#pragma unroll
    for (int off = 32; off; off >>= 1) m = fmaxf(m, __shfl_xor(m, off));
    float e = expf(v - m);
    float s = e;
#pragma unroll
    for (int off = 32; off; off >>= 1) s += __shfl_xor(s, off);
    *p = e / s;
}

// ---------------- bilinear sampling + attention weighting ------------------------
// 8 lanes per (b,q,h); each lane covers 4 channels via float4. Corner loads:
// 8 lanes x 16B = one 128B row of v. loc/attn read as float4 (4 pts per load).
// Output written directly as bf16 (feeds the MFMA out-projection GEMM).
__global__ __launch_bounds__(256) void sample_kernel(const float* __restrict__ v,
                                                     const float* __restrict__ loc,
                                                     const float* __restrict__ attn,
                                                     unsigned short* __restrict__ interm) {
    const int g  = blockIdx.x * 32 + (threadIdx.x >> 3);  // (b*1024+q)*8 + h
    const int l8 = threadIdx.x & 7;
    const int h  = g & 7, bq = g >> 3, b = bq >> 10;
    const float* lp = loc  + (size_t)g * 128;
    const float* ap = attn + (size_t)g * 64;
    const float* vb = v + (size_t)b * LV * EMB + h * HD + l8 * 4;
    float ax = 0.f, ay = 0.f, az = 0.f, aw = 0.f;
    int start = 0;
#pragma unroll
    for (int l = 0; l < 4; ++l) {
        const int W = 64 >> l;
        const float Wf = (float)W;
        const float* vl = vb + (size_t)start * EMB;
        const int sh = 6 - l;

        auto point = [&](float lx, float ly, float wt) {
            const float x = lx * Wf - 0.5f, y = ly * Wf - 0.5f;
            const float x0f = floorf(x), y0f = floorf(y);
            const float wx = x - x0f, wy = y - y0f;
            const int x0 = (int)x0f, y0 = (int)y0f;
            const int x1 = x0 + 1, y1 = y0 + 1;
            const float iwx = 1.f - wx, iwy = 1.f - wy;
            float w00 = iwx * iwy * wt, w10 = wx * iwy * wt;
            float w01 = iwx * wy * wt,  w11 = wx * wy * wt;
            const bool vx0 = (x0 >= 0) & (x0 < W);
            const bool vx1 = (x1 >= 0) & (x1 < W);
            const bool vy0 = (y0 >= 0) & (y0 < W);
            const bool vy1 = (y1 >= 0) & (y1 < W);
            w00 = (vx0 & vy0) ? w00 : 0.f;
            w10 = (vx1 & vy0) ? w10 : 0.f;
            w01 = (vx0 & vy1) ? w01 : 0.f;
            w11 = (vx1 & vy1) ? w11 : 0.f;
            const int cx0 = min(max(x0, 0), W - 1);
            const int cx1 = min(max(x1, 0), W - 1);
            const int cy0 = min(max(y0, 0), W - 1);
            const int cy1 = min(max(y1, 0), W - 1);
            const float4 g00 = *(const float4*)(vl + (size_t)((cy0 << sh) + cx0) * EMB);
            const float4 g10 = *(const float4*)(vl + (size_t)((cy0 << sh) + cx1) * EMB);
            const float4 g01 = *(const float4*)(vl + (size_t)((cy1 << sh) + cx0) * EMB);
            const float4 g11 = *(const float4*)(vl + (size_t)((cy1 << sh) + cx1) * EMB);
            ax += w00 * g00.x + w10 * g10.x + w01 * g01.x + w11 * g11.x;
            ay += w00 * g00.y + w10 * g10.y + w01 * g01.y + w11 * g11.y;
            az += w00 * g00.z + w10 * g10.z + w01 * g01.z + w11 * g11.z;
            aw += w00 * g00.w + w10 * g10.w + w01 * g01.w + w11 * g11.w;
        };

#pragma unroll
        for (int p4 = 0; p4 < 16; p4 += 4) {
            const int i = l * 16 + p4;
            const float4 la = *(const float4*)(lp + 2 * i);
            const float4 lb = *(const float4*)(lp + 2 * i + 4);
            const float4 wv = *(const float4*)(ap + i);
            point(la.x, la.y, wv.x); point(la.z, la.w, wv.y);
            point(lb.x, lb.y, wv.z); point(lb.z, lb.w, wv.w);
        }
        start += W * W;
    }
    unsigned short o[4] = {f2bf(ax), f2bf(ay), f2bf(az), f2bf(aw)};
    *(ushort4*)(interm + (size_t)bq * EMB + h * HD + l8 * 4) = *(const ushort4*)o;
}

// ---------------- host launch ----------------------------------------------------
extern "C" void kernel_launch(void* const* d_in, const int* in_sizes, int n_in,
                              void* d_out, int out_size, void* d_ws, size_t ws_size,
                              hipStream_t stream) {
    const float* query   = (const float*)d_in[0];
    const float* refp    = (const float*)d_in[1];
    const float* value   = (const float*)d_in[2];
    const float* W_value = (const float*)d_in[3];
    const float* b_value = (const float*)d_in[4];
    const float* W_off   = (const float*)d_in[5];
    const float* b_off   = (const float*)d_in[6];
    const float* W_attn  = (const float*)d_in[7];
    const float* b_attn  = (const float*)d_in[8];
    const float* W_out   = (const float*)d_in[9];
    const float* b_out   = (const float*)d_in[10];

    float* out      = (float*)d_out;            // [4,1024,256]
    float* loc_out  = out + 1048576;            // [4,1024,8,4,16,2]
    float* attn_out = out + 5242880;            // [4,1024,8,4,16]

    // workspace layout (25.4 MB total)
    char* ws = (char*)d_ws;
    float*          v_proj   = (float*)ws;                         // 22,282,240 B
    unsigned short* interm   = (unsigned short*)(ws + 22282240);   //  2,097,152 B
    unsigned short* Wv_t     = (unsigned short*)(ws + 24379392);   //    131,072 B
    unsigned short* Woff_t   = (unsigned short*)(ws + 24510464);   //    524,288 B
    unsigned short* Wat_t    = (unsigned short*)(ws + 25034752);   //    262,144 B
    unsigned short* Wout_t   = (unsigned short*)(ws + 25296896);   //    131,072 B

    const dim3 blk(256);

    // transpose+convert weights to bf16 [N][K]
    convT<<<dim3(256 / 32, 8),  blk, 0, stream>>>(W_value, Wv_t,   256);
    convT<<<dim3(1024 / 32, 8), blk, 0, stream>>>(W_off,   Woff_t, 1024);
    convT<<<dim3(512 / 32, 8),  blk, 0, stream>>>(W_attn,  Wat_t,  512);
    convT<<<dim3(256 / 32, 8),  blk, 0, stream>>>(W_out,   Wout_t, 256);

    // v = value @ W_value + b  -> fp32 v_proj
    gemm_mfma<true><<<dim3(256 / 64, 21760 / 64), blk, 0, stream>>>(
        value, Wv_t, b_value, v_proj, 21760, 256);
    // raw offsets -> loc region
    gemm_mfma<true><<<dim3(1024 / 64, 4096 / 64), blk, 0, stream>>>(
        query, Woff_t, b_off, loc_out, 4096, 1024);
    // attn logits -> attn region
    gemm_mfma<true><<<dim3(512 / 64, 4096 / 64), blk, 0, stream>>>(
        query, Wat_t, b_attn, attn_out, 4096, 512);

    loc_kernel<<<2097152 / 256, blk, 0, stream>>>(refp, loc_out);
    softmax64<<<(BS * LQ * NH) / 4, blk, 0, stream>>>(attn_out);

    sample_kernel<<<(BS * LQ * NH) / 32, blk, 0, stream>>>(v_proj, loc_out, attn_out, interm);

    // output = interm @ W_out + b  (A is bf16)
    gemm_mfma<false><<<dim3(256 / 64, 4096 / 64), blk, 0, stream>>>(
        interm, Wout_t, b_out, out, 4096, 256);
}

// Round 3
// 184.729 us; speedup vs baseline: 2.0678x; 1.0921x over previous
//
#include <hip/hip_runtime.h>
#include <math.h>

// Problem constants
#define BS 4
#define LQ 1024
#define EMB 256
#define NH 8
#define NL 4
#define NP 16
#define HD 32
#define LV 5440   // 64*64 + 32*32 + 16*16 + 8*8
#define KDIM 256  // all GEMMs have K = 256

typedef __attribute__((ext_vector_type(8))) short short8;  // 8 bf16 = 4 VGPRs
typedef __attribute__((ext_vector_type(4))) float f32x4;

__device__ inline unsigned short f2bf(float f) {
    unsigned u = __builtin_bit_cast(unsigned, f);
    u += 0x7fff + ((u >> 16) & 1);   // round-to-nearest-even
    return (unsigned short)(u >> 16);
}

// ---- all 4 weights [K=256][N] fp32 -> Wt_all[2048][256] bf16 (transpose+convert)
// col map: 0..255 W_value | 256..1279 W_off | 1280..1791 W_attn | 1792..2047 W_out
__global__ __launch_bounds__(256) void convT_all(const float* __restrict__ Wv,
                                                 const float* __restrict__ Wo,
                                                 const float* __restrict__ Wa,
                                                 const float* __restrict__ Wu,
                                                 unsigned short* __restrict__ Wt) {
    __shared__ float tile[32][33];
    const int n0 = blockIdx.x * 32, k0 = blockIdx.y * 32;
    const float* src; int N, nloc;
    if (n0 < 256)       { src = Wv; N = 256;  nloc = n0; }
    else if (n0 < 1280) { src = Wo; N = 1024; nloc = n0 - 256; }
    else if (n0 < 1792) { src = Wa; N = 512;  nloc = n0 - 1280; }
    else                { src = Wu; N = 256;  nloc = n0 - 1792; }
    const int tx = threadIdx.x & 31, ty = threadIdx.x >> 5;  // ty 0..7
#pragma unroll
    for (int i = 0; i < 32; i += 8)
        tile[ty + i][tx] = src[(size_t)(k0 + ty + i) * N + nloc + tx];
    __syncthreads();
#pragma unroll
    for (int i = 0; i < 32; i += 8)
        Wt[(size_t)(n0 + ty + i) * KDIM + k0 + tx] = f2bf(tile[tx][ty + i]);
}

// ---------------- bf16 MFMA GEMM, 128x128 tile (m97 structure) -------------------
// 256 threads = 4 waves in 2x2; each wave computes 64x64 via 4x4 frags of
// 16x16x32. BK=32, K=256 fixed. B staged via global_load_lds width 16.
// A: fp32 (converted in VGPRs during staging) or bf16 (glds).
// MODE 0: C[r*N+c] = acc + bias[c]
// MODE 1: fused qkv epilogue (N=1536): cols <1024 -> sampling locations with
//         reference-point polynomial; cols >=1024 -> attn logits buffer C2.
template <bool A_FP32, int MODE>
__global__ __launch_bounds__(256) void gemm128(const void* __restrict__ Aptr,
                                               const unsigned short* __restrict__ Bt,
                                               const float* __restrict__ bias,
                                               const float* __restrict__ bias2,
                                               const float* __restrict__ refp,
                                               float* __restrict__ C,
                                               float* __restrict__ C2,
                                               int N) {
    __shared__ short As[128 * 32];
    __shared__ short Bs[128 * 32];
    const int t = threadIdx.x;
    const int lane = t & 63, w = t >> 6;
    const int quad = lane >> 4, l16 = lane & 15;
    const int wr = w >> 1, wc = w & 1;
    const int row0 = blockIdx.y * 128, col0 = blockIdx.x * 128;

    f32x4 acc[4][4] = {};

    // B staging: chunk c = j*256+t covers 16B: row c>>2, k-offset (c&3)*8 elems
    const int bro = t >> 2, bko = (t & 3) * 8;
    const unsigned short* bsrc0 = Bt + (size_t)(col0 + bro) * KDIM + bko;
    const unsigned short* bsrc1 = bsrc0 + (size_t)64 * KDIM;
    short* const bdst0 = Bs + (size_t)(w * 64) * 8;          // + lane*16B by HW
    short* const bdst1 = Bs + (size_t)(256 + w * 64) * 8;

    // A staging (fp32 path): thread t covers 16 floats: row t>>1, k-half (t&1)*16
    const int ar = t >> 1, akq = (t & 1) * 16;
    const float* afsrc = (const float*)Aptr + (size_t)(row0 + ar) * KDIM + akq;
    short* const adst = As + ar * 32 + akq;
    // A staging (bf16 path): same pattern as B
    const unsigned short* absrc0 = (const unsigned short*)Aptr + (size_t)(row0 + bro) * KDIM + bko;
    const unsigned short* absrc1 = absrc0 + (size_t)64 * KDIM;
    short* const adst0 = As + (size_t)(w * 64) * 8;
    short* const adst1 = As + (size_t)(256 + w * 64) * 8;

    for (int kt = 0; kt < KDIM / 32; ++kt) {
        __syncthreads();
        __builtin_amdgcn_global_load_lds(
            (const __attribute__((address_space(1))) void*)(bsrc0 + kt * 32),
            (__attribute__((address_space(3))) void*)bdst0, 16, 0, 0);
        __builtin_amdgcn_global_load_lds(
            (const __attribute__((address_space(1))) void*)(bsrc1 + kt * 32),
            (__attribute__((address_space(3))) void*)bdst1, 16, 0, 0);
        if (A_FP32) {
            const float* s = afsrc + kt * 32;
            const float4 f0 = *(const float4*)(s);
            const float4 f1 = *(const float4*)(s + 4);
            const float4 f2 = *(const float4*)(s + 8);
            const float4 f3 = *(const float4*)(s + 12);
            short8 h0, h1;
            h0[0] = (short)f2bf(f0.x); h0[1] = (short)f2bf(f0.y);
            h0[2] = (short)f2bf(f0.z); h0[3] = (short)f2bf(f0.w);
            h0[4] = (short)f2bf(f1.x); h0[5] = (short)f2bf(f1.y);
            h0[6] = (short)f2bf(f1.z); h0[7] = (short)f2bf(f1.w);
            h1[0] = (short)f2bf(f2.x); h1[1] = (short)f2bf(f2.y);
            h1[2] = (short)f2bf(f2.z); h1[3] = (short)f2bf(f2.w);
            h1[4] = (short)f2bf(f3.x); h1[5] = (short)f2bf(f3.y);
            h1[6] = (short)f2bf(f3.z); h1[7] = (short)f2bf(f3.w);
            *(short8*)(adst)     = h0;
            *(short8*)(adst + 8) = h1;
        } else {
            __builtin_amdgcn_global_load_lds(
                (const __attribute__((address_space(1))) void*)(absrc0 + kt * 32),
                (__attribute__((address_space(3))) void*)adst0, 16, 0, 0);
            __builtin_amdgcn_global_load_lds(
                (const __attribute__((address_space(1))) void*)(absrc1 + kt * 32),
                (__attribute__((address_space(3))) void*)adst1, 16, 0, 0);
        }
        __syncthreads();

        short8 af[4], bf[4];
#pragma unroll
        for (int mi = 0; mi < 4; ++mi)
            af[mi] = *(const short8*)&As[(wr * 64 + mi * 16 + l16) * 32 + quad * 8];
#pragma unroll
        for (int ni = 0; ni < 4; ++ni)
            bf[ni] = *(const short8*)&Bs[(wc * 64 + ni * 16 + l16) * 32 + quad * 8];
#pragma unroll
        for (int mi = 0; mi < 4; ++mi)
#pragma unroll
            for (int ni = 0; ni < 4; ++ni)
                acc[mi][ni] = __builtin_amdgcn_mfma_f32_16x16x32_bf16(af[mi], bf[ni],
                                                                      acc[mi][ni], 0, 0, 0);
    }

    // C/D layout: col = lane&15, row = quad*4 + reg  [m89-verified, R2-verified]
    if (MODE == 0) {
#pragma unroll
        for (int ni = 0; ni < 4; ++ni) {
            const int c = col0 + wc * 64 + ni * 16 + l16;
            const float bv = bias[c];
#pragma unroll
            for (int mi = 0; mi < 4; ++mi) {
                const int r0 = row0 + wr * 64 + mi * 16 + quad * 4;
#pragma unroll
                for (int rr = 0; rr < 4; ++rr)
                    C[(size_t)(r0 + rr) * N + c] = acc[mi][ni][rr] + bv;
            }
        }
    } else {
        const bool is_off = (col0 < 1024);   // block-uniform (1024 % 128 == 0)
#pragma unroll
        for (int ni = 0; ni < 4; ++ni) {
            const int cg = col0 + wc * 64 + ni * 16 + l16;
            if (is_off) {
                // cg = h*128 + l*32 + p*2 + xy
                const int xy = cg & 1, p = (cg >> 1) & 15, l = (cg >> 5) & 3;
                const float lam = (float)p * (1.0f / 15.0f);
                const float l2 = lam * lam, l3 = l2 * lam;
                const float rW = (l == 0) ? 0.015625f : (l == 1) ? 0.03125f
                                : (l == 2) ? 0.0625f : 0.125f;
                const float bv = bias[cg];
#pragma unroll
                for (int mi = 0; mi < 4; ++mi) {
                    const int r0 = row0 + wr * 64 + mi * 16 + quad * 4;
#pragma unroll
                    for (int rr = 0; rr < 4; ++rr) {
                        const int r = r0 + rr;
                        const float4 rp = *(const float4*)(refp + (size_t)r * 8 + xy * 4);
                        const float poly = rp.x * l3 + rp.y * l2 + rp.z * lam + rp.w;
                        C[(size_t)r * 1024 + cg] = poly + (acc[mi][ni][rr] + bv) * rW;
                    }
                }
            } else {
                const int ca = cg - 1024;
                const float bv = bias2[ca];
#pragma unroll
                for (int mi = 0; mi < 4; ++mi) {
                    const int r0 = row0 + wr * 64 + mi * 16 + quad * 4;
#pragma unroll
                    for (int rr = 0; rr < 4; ++rr)
                        C2[(size_t)(r0 + rr) * 512 + ca] = acc[mi][ni][rr] + bv;
                }
            }
        }
    }
}

// ---------------- softmax over 64 contiguous logits, one wave per row ------------
__global__ __launch_bounds__(256) void softmax64(float* __restrict__ a) {
    const int row  = blockIdx.x * 4 + (threadIdx.x >> 6);
    const int lane = threadIdx.x & 63;
    float* p = a + (size_t)row * 64 + lane;
    float v = *p;
    float m = v;
#pragma unroll
    for (int off = 32; off; off >>= 1) m = fmaxf(m, __shfl_xor(m, off));
    float e = expf(v - m);
    float s = e;
#pragma unroll
    for (int off = 32; off; off >>= 1) s += __shfl_xor(s, off);
    *p = e / s;
}

// ---------------- bilinear sampling + attention weighting ------------------------
// 32 lanes per (b,q,h): 4 octets, one level each; lane covers 4 channels (float4).
// Cross-octet reduce via shfl_xor(8,16). 4096 blocks -> 4x the resident waves of R2.
__global__ __launch_bounds__(256) void sample_kernel(const float* __restrict__ v,
                                                     const float* __restrict__ loc,
                                                     const float* __restrict__ attn,
                                                     unsigned short* __restrict__ interm) {
    const int t = threadIdx.x;
    const int g = blockIdx.x * 8 + (t >> 5);   // (b*1024+q)*8 + h
    const int lane32 = t & 31;
    const int l8 = lane32 & 7;                 // channel quad
    const int lvl = lane32 >> 3;               // level 0..3
    const int h = g & 7, bq = g >> 3, b = bq >> 10;

    const int W = 64 >> lvl;
    const float Wf = (float)W;
    const int sh = 6 - lvl;
    const int start = (lvl == 0) ? 0 : (lvl == 1) ? 4096 : (lvl == 2) ? 5120 : 5376;

    const float* lp = loc  + (size_t)g * 128 + lvl * 32;   // this level's 16 pts
    const float* ap = attn + (size_t)g * 64  + lvl * 16;
    const float* vl = v + (size_t)b * LV * EMB + (size_t)start * EMB + h * HD + l8 * 4;

    float ax = 0.f, ay = 0.f, az = 0.f, aw = 0.f;

    auto point = [&](float lx, float ly, float wt) {
        const float x = lx * Wf - 0.5f, y = ly * Wf - 0.5f;
        const float x0f = floorf(x), y0f = floorf(y);
        const float wx = x - x0f, wy = y - y0f;
        const int x0 = (int)x0f, y0 = (int)y0f;
        const int x1 = x0 + 1, y1 = y0 + 1;
        const float iwx = 1.f - wx, iwy = 1.f - wy;
        float w00 = iwx * iwy * wt, w10 = wx * iwy * wt;
        float w01 = iwx * wy * wt,  w11 = wx * wy * wt;
        const bool vx0 = (x0 >= 0) & (x0 < W);
        const bool vx1 = (x1 >= 0) & (x1 < W);
        const bool vy0 = (y0 >= 0) & (y0 < W);
        const bool vy1 = (y1 >= 0) & (y1 < W);
        w00 = (vx0 & vy0) ? w00 : 0.f;
        w10 = (vx1 & vy0) ? w10 : 0.f;
        w01 = (vx0 & vy1) ? w01 : 0.f;
        w11 = (vx1 & vy1) ? w11 : 0.f;
        const int cx0 = min(max(x0, 0), W - 1);
        const int cx1 = min(max(x1, 0), W - 1);
        const int cy0 = min(max(y0, 0), W - 1);
        const int cy1 = min(max(y1, 0), W - 1);
        const float4 g00 = *(const float4*)(vl + (size_t)((cy0 << sh) + cx0) * EMB);
        const float4 g10 = *(const float4*)(vl + (size_t)((cy0 << sh) + cx1) * EMB);
        const float4 g01 = *(const float4*)(vl + (size_t)((cy1 << sh) + cx0) * EMB);
        const float4 g11 = *(const float4*)(vl + (size_t)((cy1 << sh) + cx1) * EMB);
        ax += w00 * g00.x + w10 * g10.x + w01 * g01.x + w11 * g11.x;
        ay += w00 * g00.y + w10 * g10.y + w01 * g01.y + w11 * g11.y;
        az += w00 * g00.z + w10 * g10.z + w01 * g01.z + w11 * g11.z;
        aw += w00 * g00.w + w10 * g10.w + w01 * g01.w + w11 * g11.w;
    };

#pragma unroll
    for (int p4 = 0; p4 < 16; p4 += 4) {
        const float4 la = *(const float4*)(lp + 2 * p4);
        const float4 lb = *(const float4*)(lp + 2 * p4 + 4);
        const float4 wv = *(const float4*)(ap + p4);
        point(la.x, la.y, wv.x); point(la.z, la.w, wv.y);
        point(lb.x, lb.y, wv.z); point(lb.z, lb.w, wv.w);
    }

    // reduce across the 4 level-octets (lane bits 3,4)
#pragma unroll
    for (int m = 8; m <= 16; m <<= 1) {
        ax += __shfl_xor(ax, m); ay += __shfl_xor(ay, m);
        az += __shfl_xor(az, m); aw += __shfl_xor(aw, m);
    }

    if (lvl == 0) {
        unsigned short o[4] = {f2bf(ax), f2bf(ay), f2bf(az), f2bf(aw)};
        *(ushort4*)(interm + (size_t)bq * EMB + h * HD + l8 * 4) = *(const ushort4*)o;
    }
}

// ---------------- host launch ----------------------------------------------------
extern "C" void kernel_launch(void* const* d_in, const int* in_sizes, int n_in,
                              void* d_out, int out_size, void* d_ws, size_t ws_size,
                              hipStream_t stream) {
    const float* query   = (const float*)d_in[0];
    const float* refp    = (const float*)d_in[1];
    const float* value   = (const float*)d_in[2];
    const float* W_value = (const float*)d_in[3];
    const float* b_value = (const float*)d_in[4];
    const float* W_off   = (const float*)d_in[5];
    const float* b_off   = (const float*)d_in[6];
    const float* W_attn  = (const float*)d_in[7];
    const float* b_attn  = (const float*)d_in[8];
    const float* W_out   = (const float*)d_in[9];
    const float* b_out   = (const float*)d_in[10];

    float* out      = (float*)d_out;            // [4,1024,256]
    float* loc_out  = out + 1048576;            // [4,1024,8,4,16,2]
    float* attn_out = out + 5242880;            // [4,1024,8,4,16]

    // workspace layout (25,427,968 B — identical footprint to R2)
    char* ws = (char*)d_ws;
    float*          v_proj = (float*)ws;                          // 22,282,240 B
    unsigned short* interm = (unsigned short*)(ws + 22282240);    //  2,097,152 B
    unsigned short* Wt_all = (unsigned short*)(ws + 24379392);    //  1,048,576 B

    const dim3 blk(256);

    // transpose+convert all weights -> Wt_all[2048][256] bf16
    convT_all<<<dim3(2048 / 32, 8), blk, 0, stream>>>(W_value, W_off, W_attn, W_out, Wt_all);

    // v = value @ W_value + b  -> fp32 v_proj
    gemm128<true, 0><<<dim3(2, 170), blk, 0, stream>>>(
        value, Wt_all, b_value, nullptr, nullptr, v_proj, nullptr, 256);

    // fused offsets+attn GEMM (N=1536) with loc-poly epilogue
    gemm128<true, 1><<<dim3(12, 32), blk, 0, stream>>>(
        query, Wt_all + (size_t)256 * KDIM, b_off, b_attn, refp, loc_out, attn_out, 1536);

    softmax64<<<(BS * LQ * NH) / 4, blk, 0, stream>>>(attn_out);

    sample_kernel<<<(BS * LQ * NH) / 8, blk, 0, stream>>>(v_proj, loc_out, attn_out, interm);

    // output = interm @ W_out + b  (A bf16)
    gemm128<false, 0><<<dim3(2, 32), blk, 0, stream>>>(
        interm, Wt_all + (size_t)1792 * KDIM, b_out, nullptr, nullptr, out, nullptr, 256);
}